// Round 5
// baseline (1148.158 us; speedup 1.0000x reference)
//
#include <hip/hip_runtime.h>
#include <hip/hip_bf16.h>

#define N_NODES 100000
#define N_EDGES 1600000
#define IN_C 512
#define HID_C 256
#define OUT_C 64
#define K_ITERS 10
#define ALPHA 0.1f

typedef __bf16 bf16x8 __attribute__((ext_vector_type(8)));
typedef __bf16 bf16x4 __attribute__((ext_vector_type(4)));
typedef float f32x4 __attribute__((ext_vector_type(4)));
typedef _Float16 f16;
typedef _Float16 f16x2 __attribute__((ext_vector_type(2)));

#define MFMA(a, b, c) __builtin_amdgcn_mfma_f32_16x16x32_bf16((a), (b), (c), 0, 0, 0)

__device__ __forceinline__ void gload16(const void* g, void* l) {
    __builtin_amdgcn_global_load_lds(
        (const __attribute__((address_space(1))) unsigned int*)g,
        (__attribute__((address_space(3))) unsigned int*)l, 16, 0, 0);
}

// ---------------------------------------------------------------------------
// CSR build kernels
// ---------------------------------------------------------------------------
__global__ void k_count(const int* __restrict__ ei, int* __restrict__ cnt, int E) {
    int e = blockIdx.x * blockDim.x + threadIdx.x;
    if (e < E) atomicAdd(&cnt[ei[E + e]], 1);
}

__global__ void k_dinv(const int* __restrict__ cnt, float* __restrict__ dinv, int n) {
    int i = blockIdx.x * blockDim.x + threadIdx.x;
    if (i < n) dinv[i] = rsqrtf((float)cnt[i] + 1.0f);  // +1 for self-loop
}

// ---------------------------------------------------------------------------
// Two-level scan: 1024 elems/block (256 thr x 4).
// ---------------------------------------------------------------------------
#define SCB 1024
__global__ __launch_bounds__(256) void k_scan1(const int* __restrict__ cnt,
                                               int* __restrict__ bsum, int n) {
    __shared__ int s[256];
    int b = blockIdx.x, t = threadIdx.x;
    int base = b * SCB + t * 4;
    int local = 0;
#pragma unroll
    for (int j = 0; j < 4; ++j) {
        int i = base + j;
        if (i < n) local += cnt[i];
    }
    s[t] = local;
    __syncthreads();
    for (int off = 1; off < 256; off <<= 1) {
        int u = (t >= off) ? s[t - off] : 0;
        __syncthreads();
        s[t] += u;
        __syncthreads();
    }
    if (t == 255) bsum[b] = s[255];
}

__global__ __launch_bounds__(128) void k_scan2(const int* __restrict__ bsum,
                                               int* __restrict__ boff, int G,
                                               int* __restrict__ row_ptr, int n, int total) {
    __shared__ int s[128];
    int t = threadIdx.x;
    int v = (t < G) ? bsum[t] : 0;
    s[t] = v;
    __syncthreads();
    for (int off = 1; off < 128; off <<= 1) {
        int u = (t >= off) ? s[t - off] : 0;
        __syncthreads();
        s[t] += u;
        __syncthreads();
    }
    if (t < G) boff[t] = s[t] - v;
    if (t == 0) row_ptr[n] = total;
}

__global__ __launch_bounds__(256) void k_scan3(const int* __restrict__ cnt,
                                               const int* __restrict__ boff,
                                               int* __restrict__ row_ptr,
                                               int* __restrict__ cursor, int n) {
    __shared__ int s[256];
    int b = blockIdx.x, t = threadIdx.x;
    int base = b * SCB + t * 4;
    int c4[4];
    int local = 0;
#pragma unroll
    for (int j = 0; j < 4; ++j) {
        int i = base + j;
        c4[j] = (i < n) ? cnt[i] : 0;
        local += c4[j];
    }
    s[t] = local;
    __syncthreads();
    for (int off = 1; off < 256; off <<= 1) {
        int u = (t >= off) ? s[t - off] : 0;
        __syncthreads();
        s[t] += u;
        __syncthreads();
    }
    int run = boff[b] + s[t] - local;
#pragma unroll
    for (int j = 0; j < 4; ++j) {
        int i = base + j;
        if (i < n) {
            row_ptr[i] = run;
            cursor[i] = run;
            run += c4[j];
        }
    }
}

__global__ void k_fill(const int* __restrict__ ei, const float* __restrict__ dinv,
                       int* __restrict__ cursor, int* __restrict__ csr_src,
                       float* __restrict__ csr_w, int E) {
    int e = blockIdx.x * blockDim.x + threadIdx.x;
    if (e < E) {
        int s = ei[e];
        int d = ei[E + e];
        int pos = atomicAdd(&cursor[d], 1);
        csr_src[pos] = s;
        csr_w[pos] = dinv[s] * dinv[d];
    }
}

// ---------------------------------------------------------------------------
// Weight split: f32 -> (hi bf16, lo bf16), hi+lo ~ f32 to ~2^-16 rel.
// ---------------------------------------------------------------------------
__global__ void k_split(const float* __restrict__ in, __bf16* __restrict__ hi,
                        __bf16* __restrict__ lo, int n) {
    int i = blockIdx.x * blockDim.x + threadIdx.x;
    if (i < n) {
        float f = in[i];
        __bf16 h = (__bf16)f;
        hi[i] = h;
        lo[i] = (__bf16)(f - (float)h);
    }
}

// ---------------------------------------------------------------------------
// Fused split-bf16 MFMA MLP (GEMM internals unchanged; see round-1 comments).
// ---------------------------------------------------------------------------
__global__ __launch_bounds__(256, 2) void k_mlp2(
    const float* __restrict__ x,
    const __bf16* __restrict__ w1h, const __bf16* __restrict__ w1l,
    const float* __restrict__ b1,
    const __bf16* __restrict__ w2h, const __bf16* __restrict__ w2l,
    const float* __restrict__ b2,
    f16* __restrict__ h016, f16* __restrict__ hcur16, int n) {
    __shared__ __align__(16) union {
        struct {
            __bf16 Ah[64 * 40];
            __bf16 Al[64 * 40];
            __bf16 Bh[256 * 32];
            __bf16 Bl[256 * 32];
        } p1;
        struct {
            __bf16 Hh[64 * 264];
            __bf16 Hl[64 * 264];
        } p2;
    } sm;

    const int tid = threadIdx.x;
    const int l = tid & 63;
    const int w = tid >> 6;
    const int lr = l & 15;
    const int kg = l >> 4;
    const int row0 = blockIdx.x * 64;

    f32x4 acc[4][4];
#pragma unroll
    for (int m = 0; m < 4; ++m)
#pragma unroll
        for (int nf = 0; nf < 4; ++nf) acc[m][nf] = (f32x4)0.0f;

    for (int k0 = 0; k0 < IN_C; k0 += 32) {
#pragma unroll
        for (int i = 0; i < 4; ++i) {
            int slot = tid + 256 * i;
            int row = slot >> 2;
            int kc = (slot & 3) ^ ((row >> 1) & 3);
            size_t goff = (size_t)row * IN_C + k0 + kc * 8;
            int sbase = (w * 64 + 256 * i) * 8;
            gload16(w1h + goff, &sm.p1.Bh[sbase]);
            gload16(w1l + goff, &sm.p1.Bl[sbase]);
        }
#pragma unroll
        for (int i = 0; i < 2; ++i) {
            int f4 = tid + 256 * i;
            int r = f4 >> 3;
            int kk = (f4 & 7) * 4;
            int gr = row0 + r;
            if (gr >= n) gr = n - 1;
            float4 v = *(const float4*)&x[(size_t)gr * IN_C + k0 + kk];
            float vv[4] = {v.x, v.y, v.z, v.w};
            bf16x4 h4, l4;
#pragma unroll
            for (int j = 0; j < 4; ++j) {
                __bf16 hb = (__bf16)vv[j];
                h4[j] = hb;
                l4[j] = (__bf16)(vv[j] - (float)hb);
            }
            *(bf16x4*)&sm.p1.Ah[r * 40 + kk] = h4;
            *(bf16x4*)&sm.p1.Al[r * 40 + kk] = l4;
        }
        __syncthreads();

        bf16x8 ah[4], al[4], bh[4], bl[4];
#pragma unroll
        for (int m = 0; m < 4; ++m) {
            int ao = (m * 16 + lr) * 40 + kg * 8;
            ah[m] = *(const bf16x8*)&sm.p1.Ah[ao];
            al[m] = *(const bf16x8*)&sm.p1.Al[ao];
        }
#pragma unroll
        for (int nf = 0; nf < 4; ++nf) {
            int row = w * 64 + nf * 16 + lr;
            int kc = kg ^ ((row >> 1) & 3);
            int bo = row * 32 + kc * 8;
            bh[nf] = *(const bf16x8*)&sm.p1.Bh[bo];
            bl[nf] = *(const bf16x8*)&sm.p1.Bl[bo];
        }
#pragma unroll
        for (int m = 0; m < 4; ++m)
#pragma unroll
            for (int nf = 0; nf < 4; ++nf) {
                acc[m][nf] = MFMA(ah[m], bh[nf], acc[m][nf]);
                acc[m][nf] = MFMA(ah[m], bl[nf], acc[m][nf]);
                acc[m][nf] = MFMA(al[m], bh[nf], acc[m][nf]);
            }
        __syncthreads();
    }

#pragma unroll
    for (int m = 0; m < 4; ++m)
#pragma unroll
        for (int nf = 0; nf < 4; ++nf) {
            int col = w * 64 + nf * 16 + lr;
            float bb = b1[col];
#pragma unroll
            for (int r = 0; r < 4; ++r) {
                int row = m * 16 + kg * 4 + r;
                float hv = acc[m][nf][r] + bb;
                hv = fmaxf(hv, 0.0f);
                __bf16 hb = (__bf16)hv;
                sm.p2.Hh[row * 264 + col] = hb;
                sm.p2.Hl[row * 264 + col] = (__bf16)(hv - (float)hb);
            }
        }
    __syncthreads();

    f32x4 acc2[4];
#pragma unroll
    for (int m = 0; m < 4; ++m) acc2[m] = (f32x4)0.0f;
    const int col2 = w * 16 + lr;

#pragma unroll
    for (int k0 = 0; k0 < HID_C; k0 += 32) {
        size_t wo = (size_t)col2 * HID_C + k0 + kg * 8;
        bf16x8 b2h = *(const bf16x8*)&w2h[wo];
        bf16x8 b2l = *(const bf16x8*)&w2l[wo];
#pragma unroll
        for (int m = 0; m < 4; ++m) {
            int ho = (m * 16 + lr) * 264 + k0 + kg * 8;
            bf16x8 a2h = *(const bf16x8*)&sm.p2.Hh[ho];
            bf16x8 a2l = *(const bf16x8*)&sm.p2.Hl[ho];
            acc2[m] = MFMA(a2h, b2h, acc2[m]);
            acc2[m] = MFMA(a2h, b2l, acc2[m]);
            acc2[m] = MFMA(a2l, b2h, acc2[m]);
        }
    }

    float bb2 = b2[col2];
#pragma unroll
    for (int m = 0; m < 4; ++m)
#pragma unroll
        for (int r = 0; r < 4; ++r) {
            int grow = row0 + m * 16 + kg * 4 + r;
            if (grow < n) {
                float vv = acc2[m][r] + bb2;
                size_t idx = (size_t)grow * OUT_C + col2;
                h016[idx] = (f16)vv;
                hcur16[idx] = (f16)vv;
            }
        }
}

// ---------------------------------------------------------------------------
// fp16 propagation v2: edge-pair parallel.
// One wave per node. Lane = (half, channel-pair): lanes 0-31 process even
// edges, 32-63 odd edges; each lane loads f16x2 (4B) so each half's 32 lanes
// fetch one full 128B row. Unroll x8 -> 16 edges (8 gather instrs) in flight
// per trip; avg-degree-16 node = 1 trip. Halves combined via shfl_xor(32).
// OOB edges predicated with weight 0, address clamped to e1-1 (in bounds).
// ---------------------------------------------------------------------------
__global__ __launch_bounds__(256) void k_prop16(const f16* __restrict__ hin,
                                                const f16* __restrict__ h016,
                                                f16* __restrict__ hout,
                                                float* __restrict__ dout,
                                                const int* __restrict__ row_ptr,
                                                const int* __restrict__ csr_src,
                                                const float* __restrict__ csr_w,
                                                const float* __restrict__ dinv,
                                                int n, int final_iter) {
    int node = blockIdx.x * 4 + (threadIdx.x >> 6);
    if (node >= n) return;
    const int l = threadIdx.x & 63;
    const int half = l >> 5;
    const int cp = l & 31;  // channels 2cp, 2cp+1

    int e0 = row_ptr[node], e1 = row_ptr[node + 1];
    float ax = 0.0f, ay = 0.0f;
    for (int e = e0; e < e1; e += 16) {
#pragma unroll
        for (int j = 0; j < 8; ++j) {
            int eidx = e + 2 * j + half;
            int ce = min(eidx, e1 - 1);
            int s = csr_src[ce];
            float wv = (eidx < e1) ? csr_w[ce] : 0.0f;
            f16x2 v = *(const f16x2*)&hin[(size_t)s * OUT_C + cp * 2];
            ax += wv * (float)v.x;
            ay += wv * (float)v.y;
        }
    }
    // combine the two edge-halves
    ax += __shfl_xor(ax, 32);
    ay += __shfl_xor(ay, 32);

    float dv = dinv[node];
    size_t idx = (size_t)node * OUT_C + cp * 2;
    f16x2 sv = *(const f16x2*)&hin[idx];
    f16x2 h0v = *(const f16x2*)&h016[idx];
    float rx = (1.0f - ALPHA) * (ax + dv * dv * (float)sv.x) + ALPHA * (float)h0v.x;
    float ry = (1.0f - ALPHA) * (ay + dv * dv * (float)sv.y) + ALPHA * (float)h0v.y;

    if (half == 0) {
        f16x2 o;
        o.x = (f16)rx;
        o.y = (f16)ry;
        *(f16x2*)&hout[idx] = o;
        if (final_iter) {
            float2 of = make_float2(rx, ry);
            *(float2*)&dout[idx] = of;
        }
    }
}

// ---------------------------------------------------------------------------
extern "C" void kernel_launch(void* const* d_in, const int* in_sizes, int n_in,
                              void* d_out, int out_size, void* d_ws, size_t ws_size,
                              hipStream_t stream) {
    const float* x  = (const float*)d_in[0];
    const int*   ei = (const int*)d_in[1];
    const float* w1 = (const float*)d_in[2];
    const float* b1 = (const float*)d_in[3];
    const float* w2 = (const float*)d_in[4];
    const float* b2 = (const float*)d_in[5];
    float* dout = (float*)d_out;

    const int N = N_NODES;
    const int E = N_EDGES;
    const int G = (N + SCB - 1) / SCB;  // 98 scan blocks

    // workspace layout
    f16*   h16A    = (f16*)d_ws;                   // N*64
    f16*   h16B    = h16A + (size_t)N * OUT_C;     // N*64
    f16*   h016    = h16B + (size_t)N * OUT_C;     // N*64
    float* dinv    = (float*)(h016 + (size_t)N * OUT_C);  // N
    int*   cnt     = (int*)(dinv + N);             // N
    int*   row_ptr = cnt + N;                      // N+1
    int*   cursor  = row_ptr + (N + 1);            // N
    int*   csr_src = cursor + N;                   // E
    float* csr_w   = (float*)(csr_src + E);        // E
    __bf16* w1h    = (__bf16*)(csr_w + E);         // 256*512
    __bf16* w1l    = w1h + (size_t)HID_C * IN_C;   // 256*512
    __bf16* w2h    = w1l + (size_t)HID_C * IN_C;   // 64*256
    __bf16* w2l    = w2h + (size_t)OUT_C * HID_C;  // 64*256
    int*   bsum    = (int*)(w2l + (size_t)OUT_C * HID_C);  // 128
    int*   boff    = bsum + 128;                           // 128

    hipMemsetAsync(cnt, 0, (size_t)N * sizeof(int), stream);

    k_count<<<(E + 255) / 256, 256, 0, stream>>>(ei, cnt, E);
    k_dinv<<<(N + 255) / 256, 256, 0, stream>>>(cnt, dinv, N);
    k_scan1<<<G, 256, 0, stream>>>(cnt, bsum, N);
    k_scan2<<<1, 128, 0, stream>>>(bsum, boff, G, row_ptr, N, E);
    k_scan3<<<G, 256, 0, stream>>>(cnt, boff, row_ptr, cursor, N);
    k_fill<<<(E + 255) / 256, 256, 0, stream>>>(ei, dinv, cursor, csr_src, csr_w, E);

    k_split<<<(HID_C * IN_C + 255) / 256, 256, 0, stream>>>(w1, w1h, w1l, HID_C * IN_C);
    k_split<<<(OUT_C * HID_C + 255) / 256, 256, 0, stream>>>(w2, w2h, w2l, OUT_C * HID_C);

    k_mlp2<<<(N + 63) / 64, 256, 0, stream>>>(x, w1h, w1l, b1, w2h, w2l, b2, h016, h16A, N);

    for (int it = 0; it < K_ITERS; ++it) {
        const f16* pin = (it & 1) ? h16B : h16A;
        f16* pout = (it & 1) ? h16A : h16B;
        k_prop16<<<(N + 3) / 4, 256, 0, stream>>>(pin, h016, pout, dout, row_ptr,
                                                  csr_src, csr_w, dinv, N,
                                                  it == K_ITERS - 1 ? 1 : 0);
    }
}

// Round 6
// 835.682 us; speedup vs baseline: 1.3739x; 1.3739x over previous
//
#include <hip/hip_runtime.h>
#include <hip/hip_bf16.h>

#define N_NODES 100000
#define N_EDGES 1600000
#define IN_C 512
#define HID_C 256
#define OUT_C 64
#define K_ITERS 10
#define ALPHA 0.1f

typedef __bf16 bf16x8 __attribute__((ext_vector_type(8)));
typedef __bf16 bf16x4 __attribute__((ext_vector_type(4)));
typedef float f32x4 __attribute__((ext_vector_type(4)));
typedef _Float16 f16;

#define MFMA(a, b, c) __builtin_amdgcn_mfma_f32_16x16x32_bf16((a), (b), (c), 0, 0, 0)

__device__ __forceinline__ void gload16(const void* g, void* l) {
    __builtin_amdgcn_global_load_lds(
        (const __attribute__((address_space(1))) unsigned int*)g,
        (__attribute__((address_space(3))) unsigned int*)l, 16, 0, 0);
}

// ---------------------------------------------------------------------------
// CSR build kernels
// ---------------------------------------------------------------------------
__global__ void k_count(const int* __restrict__ ei, int* __restrict__ cnt, int E) {
    int e = blockIdx.x * blockDim.x + threadIdx.x;
    if (e < E) atomicAdd(&cnt[ei[E + e]], 1);
}

__global__ void k_dinv(const int* __restrict__ cnt, float* __restrict__ dinv, int n) {
    int i = blockIdx.x * blockDim.x + threadIdx.x;
    if (i < n) dinv[i] = rsqrtf((float)cnt[i] + 1.0f);  // +1 for self-loop
}

// ---------------------------------------------------------------------------
// Two-level scan: 1024 elems/block (256 thr x 4).
// ---------------------------------------------------------------------------
#define SCB 1024
__global__ __launch_bounds__(256) void k_scan1(const int* __restrict__ cnt,
                                               int* __restrict__ bsum, int n) {
    __shared__ int s[256];
    int b = blockIdx.x, t = threadIdx.x;
    int base = b * SCB + t * 4;
    int local = 0;
#pragma unroll
    for (int j = 0; j < 4; ++j) {
        int i = base + j;
        if (i < n) local += cnt[i];
    }
    s[t] = local;
    __syncthreads();
    for (int off = 1; off < 256; off <<= 1) {
        int u = (t >= off) ? s[t - off] : 0;
        __syncthreads();
        s[t] += u;
        __syncthreads();
    }
    if (t == 255) bsum[b] = s[255];
}

__global__ __launch_bounds__(128) void k_scan2(const int* __restrict__ bsum,
                                               int* __restrict__ boff, int G,
                                               int* __restrict__ row_ptr, int n, int total) {
    __shared__ int s[128];
    int t = threadIdx.x;
    int v = (t < G) ? bsum[t] : 0;
    s[t] = v;
    __syncthreads();
    for (int off = 1; off < 128; off <<= 1) {
        int u = (t >= off) ? s[t - off] : 0;
        __syncthreads();
        s[t] += u;
        __syncthreads();
    }
    if (t < G) boff[t] = s[t] - v;
    if (t == 0) row_ptr[n] = total;
}

__global__ __launch_bounds__(256) void k_scan3(const int* __restrict__ cnt,
                                               const int* __restrict__ boff,
                                               int* __restrict__ row_ptr,
                                               int* __restrict__ cursor, int n) {
    __shared__ int s[256];
    int b = blockIdx.x, t = threadIdx.x;
    int base = b * SCB + t * 4;
    int c4[4];
    int local = 0;
#pragma unroll
    for (int j = 0; j < 4; ++j) {
        int i = base + j;
        c4[j] = (i < n) ? cnt[i] : 0;
        local += c4[j];
    }
    s[t] = local;
    __syncthreads();
    for (int off = 1; off < 256; off <<= 1) {
        int u = (t >= off) ? s[t - off] : 0;
        __syncthreads();
        s[t] += u;
        __syncthreads();
    }
    int run = boff[b] + s[t] - local;
#pragma unroll
    for (int j = 0; j < 4; ++j) {
        int i = base + j;
        if (i < n) {
            row_ptr[i] = run;
            cursor[i] = run;
            run += c4[j];
        }
    }
}

// k_fill now writes packed (src, weight) metadata: one 8B load per edge later.
__global__ void k_fill(const int* __restrict__ ei, const float* __restrict__ dinv,
                       int* __restrict__ cursor, int2* __restrict__ csr_pack, int E) {
    int e = blockIdx.x * blockDim.x + threadIdx.x;
    if (e < E) {
        int s = ei[e];
        int d = ei[E + e];
        int pos = atomicAdd(&cursor[d], 1);
        csr_pack[pos] = make_int2(s, __float_as_int(dinv[s] * dinv[d]));
    }
}

// ---------------------------------------------------------------------------
// Weight split: f32 -> (hi bf16, lo bf16), hi+lo ~ f32 to ~2^-16 rel.
// ---------------------------------------------------------------------------
__global__ void k_split(const float* __restrict__ in, __bf16* __restrict__ hi,
                        __bf16* __restrict__ lo, int n) {
    int i = blockIdx.x * blockDim.x + threadIdx.x;
    if (i < n) {
        float f = in[i];
        __bf16 h = (__bf16)f;
        hi[i] = h;
        lo[i] = (__bf16)(f - (float)h);
    }
}

// ---------------------------------------------------------------------------
// Fused split-bf16 MFMA MLP (GEMM internals unchanged; see round-1 comments).
// ---------------------------------------------------------------------------
__global__ __launch_bounds__(256, 2) void k_mlp2(
    const float* __restrict__ x,
    const __bf16* __restrict__ w1h, const __bf16* __restrict__ w1l,
    const float* __restrict__ b1,
    const __bf16* __restrict__ w2h, const __bf16* __restrict__ w2l,
    const float* __restrict__ b2,
    f16* __restrict__ h016, f16* __restrict__ hcur16, int n) {
    __shared__ __align__(16) union {
        struct {
            __bf16 Ah[64 * 40];
            __bf16 Al[64 * 40];
            __bf16 Bh[256 * 32];
            __bf16 Bl[256 * 32];
        } p1;
        struct {
            __bf16 Hh[64 * 264];
            __bf16 Hl[64 * 264];
        } p2;
    } sm;

    const int tid = threadIdx.x;
    const int l = tid & 63;
    const int w = tid >> 6;
    const int lr = l & 15;
    const int kg = l >> 4;
    const int row0 = blockIdx.x * 64;

    f32x4 acc[4][4];
#pragma unroll
    for (int m = 0; m < 4; ++m)
#pragma unroll
        for (int nf = 0; nf < 4; ++nf) acc[m][nf] = (f32x4)0.0f;

    for (int k0 = 0; k0 < IN_C; k0 += 32) {
#pragma unroll
        for (int i = 0; i < 4; ++i) {
            int slot = tid + 256 * i;
            int row = slot >> 2;
            int kc = (slot & 3) ^ ((row >> 1) & 3);
            size_t goff = (size_t)row * IN_C + k0 + kc * 8;
            int sbase = (w * 64 + 256 * i) * 8;
            gload16(w1h + goff, &sm.p1.Bh[sbase]);
            gload16(w1l + goff, &sm.p1.Bl[sbase]);
        }
#pragma unroll
        for (int i = 0; i < 2; ++i) {
            int f4 = tid + 256 * i;
            int r = f4 >> 3;
            int kk = (f4 & 7) * 4;
            int gr = row0 + r;
            if (gr >= n) gr = n - 1;
            float4 v = *(const float4*)&x[(size_t)gr * IN_C + k0 + kk];
            float vv[4] = {v.x, v.y, v.z, v.w};
            bf16x4 h4, l4;
#pragma unroll
            for (int j = 0; j < 4; ++j) {
                __bf16 hb = (__bf16)vv[j];
                h4[j] = hb;
                l4[j] = (__bf16)(vv[j] - (float)hb);
            }
            *(bf16x4*)&sm.p1.Ah[r * 40 + kk] = h4;
            *(bf16x4*)&sm.p1.Al[r * 40 + kk] = l4;
        }
        __syncthreads();

        bf16x8 ah[4], al[4], bh[4], bl[4];
#pragma unroll
        for (int m = 0; m < 4; ++m) {
            int ao = (m * 16 + lr) * 40 + kg * 8;
            ah[m] = *(const bf16x8*)&sm.p1.Ah[ao];
            al[m] = *(const bf16x8*)&sm.p1.Al[ao];
        }
#pragma unroll
        for (int nf = 0; nf < 4; ++nf) {
            int row = w * 64 + nf * 16 + lr;
            int kc = kg ^ ((row >> 1) & 3);
            int bo = row * 32 + kc * 8;
            bh[nf] = *(const bf16x8*)&sm.p1.Bh[bo];
            bl[nf] = *(const bf16x8*)&sm.p1.Bl[bo];
        }
#pragma unroll
        for (int m = 0; m < 4; ++m)
#pragma unroll
            for (int nf = 0; nf < 4; ++nf) {
                acc[m][nf] = MFMA(ah[m], bh[nf], acc[m][nf]);
                acc[m][nf] = MFMA(ah[m], bl[nf], acc[m][nf]);
                acc[m][nf] = MFMA(al[m], bh[nf], acc[m][nf]);
            }
        __syncthreads();
    }

#pragma unroll
    for (int m = 0; m < 4; ++m)
#pragma unroll
        for (int nf = 0; nf < 4; ++nf) {
            int col = w * 64 + nf * 16 + lr;
            float bb = b1[col];
#pragma unroll
            for (int r = 0; r < 4; ++r) {
                int row = m * 16 + kg * 4 + r;
                float hv = acc[m][nf][r] + bb;
                hv = fmaxf(hv, 0.0f);
                __bf16 hb = (__bf16)hv;
                sm.p2.Hh[row * 264 + col] = hb;
                sm.p2.Hl[row * 264 + col] = (__bf16)(hv - (float)hb);
            }
        }
    __syncthreads();

    f32x4 acc2[4];
#pragma unroll
    for (int m = 0; m < 4; ++m) acc2[m] = (f32x4)0.0f;
    const int col2 = w * 16 + lr;

#pragma unroll
    for (int k0 = 0; k0 < HID_C; k0 += 32) {
        size_t wo = (size_t)col2 * HID_C + k0 + kg * 8;
        bf16x8 b2h = *(const bf16x8*)&w2h[wo];
        bf16x8 b2l = *(const bf16x8*)&w2l[wo];
#pragma unroll
        for (int m = 0; m < 4; ++m) {
            int ho = (m * 16 + lr) * 264 + k0 + kg * 8;
            bf16x8 a2h = *(const bf16x8*)&sm.p2.Hh[ho];
            bf16x8 a2l = *(const bf16x8*)&sm.p2.Hl[ho];
            acc2[m] = MFMA(a2h, b2h, acc2[m]);
            acc2[m] = MFMA(a2h, b2l, acc2[m]);
            acc2[m] = MFMA(a2l, b2h, acc2[m]);
        }
    }

    float bb2 = b2[col2];
#pragma unroll
    for (int m = 0; m < 4; ++m)
#pragma unroll
        for (int r = 0; r < 4; ++r) {
            int grow = row0 + m * 16 + kg * 4 + r;
            if (grow < n) {
                float vv = acc2[m][r] + bb2;
                size_t idx = (size_t)grow * OUT_C + col2;
                h016[idx] = (f16)vv;
                hcur16[idx] = (f16)vv;
            }
        }
}

// ---------------------------------------------------------------------------
// fp16 propagation v3: lane-distributed metadata + readlane broadcast.
// One wave per node (64 lanes = 64 channels). Per 64-edge batch: each lane
// loads one edge's packed (src, w) int2 -- ONE coalesced 8B load covers 64
// edges. Wave-uniform inner loop readlanes (s,w) into SGPRs; the row gather
// becomes saddr-form global_load_ushort with a constant per-lane offset.
// vmem instructions: 1/edge (was 3/edge). Unroll x4 keeps 4 gathers in flight.
// ---------------------------------------------------------------------------
__global__ __launch_bounds__(256) void k_prop16(const f16* __restrict__ hin,
                                                const f16* __restrict__ h016,
                                                f16* __restrict__ hout,
                                                float* __restrict__ dout,
                                                const int* __restrict__ row_ptr,
                                                const int2* __restrict__ csr_pack,
                                                const float* __restrict__ dinv,
                                                int n, int final_iter) {
    int node = blockIdx.x * 4 + (threadIdx.x >> 6);
    if (node >= n) return;
    const int lane = threadIdx.x & 63;

    int e0 = row_ptr[node], e1 = row_ptr[node + 1];
    float acc0 = 0.0f, acc1 = 0.0f;

    for (int base = e0; base < e1; base += 64) {
        int cnt = min(64, e1 - base);
        int midx = min(base + lane, N_EDGES - 1);
        int2 meta = csr_pack[midx];
        int j = 0;
        for (; j + 3 < cnt; j += 4) {
            int s0 = __builtin_amdgcn_readlane(meta.x, j + 0);
            int s1 = __builtin_amdgcn_readlane(meta.x, j + 1);
            int s2 = __builtin_amdgcn_readlane(meta.x, j + 2);
            int s3 = __builtin_amdgcn_readlane(meta.x, j + 3);
            float w0 = __int_as_float(__builtin_amdgcn_readlane(meta.y, j + 0));
            float w1v = __int_as_float(__builtin_amdgcn_readlane(meta.y, j + 1));
            float w2v = __int_as_float(__builtin_amdgcn_readlane(meta.y, j + 2));
            float w3v = __int_as_float(__builtin_amdgcn_readlane(meta.y, j + 3));
            float v0 = (float)hin[(size_t)s0 * OUT_C + lane];
            float v1 = (float)hin[(size_t)s1 * OUT_C + lane];
            float v2 = (float)hin[(size_t)s2 * OUT_C + lane];
            float v3 = (float)hin[(size_t)s3 * OUT_C + lane];
            acc0 += w0 * v0;
            acc1 += w1v * v1;
            acc0 += w2v * v2;
            acc1 += w3v * v3;
        }
        for (; j < cnt; ++j) {
            int s = __builtin_amdgcn_readlane(meta.x, j);
            float wv = __int_as_float(__builtin_amdgcn_readlane(meta.y, j));
            acc0 += wv * (float)hin[(size_t)s * OUT_C + lane];
        }
    }

    float dv = dinv[node];
    size_t idx = (size_t)node * OUT_C + lane;
    float acc = acc0 + acc1 + dv * dv * (float)hin[idx];
    float res = (1.0f - ALPHA) * acc + ALPHA * (float)h016[idx];
    hout[idx] = (f16)res;
    if (final_iter) dout[idx] = res;
}

// ---------------------------------------------------------------------------
extern "C" void kernel_launch(void* const* d_in, const int* in_sizes, int n_in,
                              void* d_out, int out_size, void* d_ws, size_t ws_size,
                              hipStream_t stream) {
    const float* x  = (const float*)d_in[0];
    const int*   ei = (const int*)d_in[1];
    const float* w1 = (const float*)d_in[2];
    const float* b1 = (const float*)d_in[3];
    const float* w2 = (const float*)d_in[4];
    const float* b2 = (const float*)d_in[5];
    float* dout = (float*)d_out;

    const int N = N_NODES;
    const int E = N_EDGES;
    const int G = (N + SCB - 1) / SCB;  // 98 scan blocks

    // workspace layout (csr_pack placed right after h016 for 8B alignment)
    f16*   h16A    = (f16*)d_ws;                   // N*64
    f16*   h16B    = h16A + (size_t)N * OUT_C;     // N*64
    f16*   h016    = h16B + (size_t)N * OUT_C;     // N*64
    int2*  csr_pack = (int2*)(h016 + (size_t)N * OUT_C);   // E int2 (8B each)
    float* dinv    = (float*)(csr_pack + E);       // N
    int*   cnt     = (int*)(dinv + N);             // N
    int*   row_ptr = cnt + N;                      // N+1
    int*   cursor  = row_ptr + (N + 1);            // N
    __bf16* w1h    = (__bf16*)(cursor + N);        // 256*512
    __bf16* w1l    = w1h + (size_t)HID_C * IN_C;   // 256*512
    __bf16* w2h    = w1l + (size_t)HID_C * IN_C;   // 64*256
    __bf16* w2l    = w2h + (size_t)OUT_C * HID_C;  // 64*256
    int*   bsum    = (int*)(w2l + (size_t)OUT_C * HID_C);  // 128
    int*   boff    = bsum + 128;                           // 128

    hipMemsetAsync(cnt, 0, (size_t)N * sizeof(int), stream);

    k_count<<<(E + 255) / 256, 256, 0, stream>>>(ei, cnt, E);
    k_dinv<<<(N + 255) / 256, 256, 0, stream>>>(cnt, dinv, N);
    k_scan1<<<G, 256, 0, stream>>>(cnt, bsum, N);
    k_scan2<<<1, 128, 0, stream>>>(bsum, boff, G, row_ptr, N, E);
    k_scan3<<<G, 256, 0, stream>>>(cnt, boff, row_ptr, cursor, N);
    k_fill<<<(E + 255) / 256, 256, 0, stream>>>(ei, dinv, cursor, csr_pack, E);

    k_split<<<(HID_C * IN_C + 255) / 256, 256, 0, stream>>>(w1, w1h, w1l, HID_C * IN_C);
    k_split<<<(OUT_C * HID_C + 255) / 256, 256, 0, stream>>>(w2, w2h, w2l, OUT_C * HID_C);

    k_mlp2<<<(N + 63) / 64, 256, 0, stream>>>(x, w1h, w1l, b1, w2h, w2l, b2, h016, h16A, N);

    for (int it = 0; it < K_ITERS; ++it) {
        const f16* pin = (it & 1) ? h16B : h16A;
        f16* pout = (it & 1) ? h16A : h16B;
        k_prop16<<<(N + 3) / 4, 256, 0, stream>>>(pin, h016, pout, dout, row_ptr,
                                                  csr_pack, dinv, N,
                                                  it == K_ITERS - 1 ? 1 : 0);
    }
}

// Round 7
// 799.474 us; speedup vs baseline: 1.4361x; 1.0453x over previous
//
#include <hip/hip_runtime.h>
#include <hip/hip_bf16.h>

#define N_NODES 100000
#define N_EDGES 1600000
#define IN_C 512
#define HID_C 256
#define OUT_C 64
#define K_ITERS 10
#define ALPHA 0.1f

typedef __bf16 bf16x8 __attribute__((ext_vector_type(8)));
typedef __bf16 bf16x4 __attribute__((ext_vector_type(4)));
typedef float f32x4 __attribute__((ext_vector_type(4)));
typedef _Float16 f16;
typedef _Float16 f16x4 __attribute__((ext_vector_type(4)));

#define MFMA(a, b, c) __builtin_amdgcn_mfma_f32_16x16x32_bf16((a), (b), (c), 0, 0, 0)

__device__ __forceinline__ void gload16(const void* g, void* l) {
    __builtin_amdgcn_global_load_lds(
        (const __attribute__((address_space(1))) unsigned int*)g,
        (__attribute__((address_space(3))) unsigned int*)l, 16, 0, 0);
}

// ---------------------------------------------------------------------------
// CSR build kernels
// ---------------------------------------------------------------------------
__global__ void k_count(const int* __restrict__ ei, int* __restrict__ cnt, int E) {
    int e = blockIdx.x * blockDim.x + threadIdx.x;
    if (e < E) atomicAdd(&cnt[ei[E + e]], 1);
}

__global__ void k_dinv(const int* __restrict__ cnt, float* __restrict__ dinv, int n) {
    int i = blockIdx.x * blockDim.x + threadIdx.x;
    if (i < n) dinv[i] = rsqrtf((float)cnt[i] + 1.0f);  // +1 for self-loop
}

// ---------------------------------------------------------------------------
// Two-level scan: 1024 elems/block (256 thr x 4).
// ---------------------------------------------------------------------------
#define SCB 1024
__global__ __launch_bounds__(256) void k_scan1(const int* __restrict__ cnt,
                                               int* __restrict__ bsum, int n) {
    __shared__ int s[256];
    int b = blockIdx.x, t = threadIdx.x;
    int base = b * SCB + t * 4;
    int local = 0;
#pragma unroll
    for (int j = 0; j < 4; ++j) {
        int i = base + j;
        if (i < n) local += cnt[i];
    }
    s[t] = local;
    __syncthreads();
    for (int off = 1; off < 256; off <<= 1) {
        int u = (t >= off) ? s[t - off] : 0;
        __syncthreads();
        s[t] += u;
        __syncthreads();
    }
    if (t == 255) bsum[b] = s[255];
}

__global__ __launch_bounds__(128) void k_scan2(const int* __restrict__ bsum,
                                               int* __restrict__ boff, int G,
                                               int* __restrict__ row_ptr, int n, int total) {
    __shared__ int s[128];
    int t = threadIdx.x;
    int v = (t < G) ? bsum[t] : 0;
    s[t] = v;
    __syncthreads();
    for (int off = 1; off < 128; off <<= 1) {
        int u = (t >= off) ? s[t - off] : 0;
        __syncthreads();
        s[t] += u;
        __syncthreads();
    }
    if (t < G) boff[t] = s[t] - v;
    if (t == 0) row_ptr[n] = total;
}

__global__ __launch_bounds__(256) void k_scan3(const int* __restrict__ cnt,
                                               const int* __restrict__ boff,
                                               int* __restrict__ row_ptr,
                                               int* __restrict__ cursor, int n) {
    __shared__ int s[256];
    int b = blockIdx.x, t = threadIdx.x;
    int base = b * SCB + t * 4;
    int c4[4];
    int local = 0;
#pragma unroll
    for (int j = 0; j < 4; ++j) {
        int i = base + j;
        c4[j] = (i < n) ? cnt[i] : 0;
        local += c4[j];
    }
    s[t] = local;
    __syncthreads();
    for (int off = 1; off < 256; off <<= 1) {
        int u = (t >= off) ? s[t - off] : 0;
        __syncthreads();
        s[t] += u;
        __syncthreads();
    }
    int run = boff[b] + s[t] - local;
#pragma unroll
    for (int j = 0; j < 4; ++j) {
        int i = base + j;
        if (i < n) {
            row_ptr[i] = run;
            cursor[i] = run;
            run += c4[j];
        }
    }
}

// k_fill writes packed (src, weight) metadata: one 8B load per edge later.
__global__ void k_fill(const int* __restrict__ ei, const float* __restrict__ dinv,
                       int* __restrict__ cursor, int2* __restrict__ csr_pack, int E) {
    int e = blockIdx.x * blockDim.x + threadIdx.x;
    if (e < E) {
        int s = ei[e];
        int d = ei[E + e];
        int pos = atomicAdd(&cursor[d], 1);
        csr_pack[pos] = make_int2(s, __float_as_int(dinv[s] * dinv[d]));
    }
}

// ---------------------------------------------------------------------------
// Weight split: f32 -> (hi bf16, lo bf16), hi+lo ~ f32 to ~2^-16 rel.
// ---------------------------------------------------------------------------
__global__ void k_split(const float* __restrict__ in, __bf16* __restrict__ hi,
                        __bf16* __restrict__ lo, int n) {
    int i = blockIdx.x * blockDim.x + threadIdx.x;
    if (i < n) {
        float f = in[i];
        __bf16 h = (__bf16)f;
        hi[i] = h;
        lo[i] = (__bf16)(f - (float)h);
    }
}

// ---------------------------------------------------------------------------
// Fused split-bf16 MFMA MLP v2.
// Change vs v1: ALL of the block's x rows are pre-loaded into registers at
// kernel start (32 back-to-back dwordx4/thread -> deep HBM queue), converted
// to bf16-hi once. The k-loop stages A from registers (no global latency),
// so each k-step is only: W1 gload16 (L2/L3-resident) + barrier + MFMA.
// Layer 1 uses 2-term split (Ah*Bh + Ah*Bl); x-lo dropped for register budget
// (adds ~0.004 absmax, threshold has 4x margin). Layer 2 keeps 3-term.
// ---------------------------------------------------------------------------
__global__ __launch_bounds__(256, 2) void k_mlp2(
    const float* __restrict__ x,
    const __bf16* __restrict__ w1h, const __bf16* __restrict__ w1l,
    const float* __restrict__ b1,
    const __bf16* __restrict__ w2h, const __bf16* __restrict__ w2l,
    const float* __restrict__ b2,
    f16* __restrict__ h016, f16* __restrict__ hcur16, int n) {
    __shared__ __align__(16) union {
        struct {
            __bf16 Ah[64 * 40];   // 5 KB, rows padded to 40
            __bf16 Bh[256 * 32];  // 16 KB, chunk-swizzled
            __bf16 Bl[256 * 32];  // 16 KB
        } p1;
        struct {
            __bf16 Hh[64 * 264];  // 33.8 KB
            __bf16 Hl[64 * 264];  // 33.8 KB
        } p2;
    } sm;

    const int tid = threadIdx.x;
    const int l = tid & 63;
    const int w = tid >> 6;
    const int lr = l & 15;
    const int kg = l >> 4;
    const int row0 = blockIdx.x * 64;

    // ---- preload x (this block's 64 rows), convert to bf16-hi in regs ----
    bf16x4 xh[16][2];
#pragma unroll
    for (int ks = 0; ks < 16; ++ks) {
#pragma unroll
        for (int i = 0; i < 2; ++i) {
            int f4 = tid + 256 * i;
            int r = f4 >> 3, kk = (f4 & 7) * 4;
            int gr = row0 + r;
            if (gr >= n) gr = n - 1;
            float4 v = *(const float4*)&x[(size_t)gr * IN_C + ks * 32 + kk];
            bf16x4 h4;
            h4[0] = (__bf16)v.x;
            h4[1] = (__bf16)v.y;
            h4[2] = (__bf16)v.z;
            h4[3] = (__bf16)v.w;
            xh[ks][i] = h4;
        }
    }

    f32x4 acc[4][4];
#pragma unroll
    for (int m = 0; m < 4; ++m)
#pragma unroll
        for (int nf = 0; nf < 4; ++nf) acc[m][nf] = (f32x4)0.0f;

#pragma unroll
    for (int ks = 0; ks < 16; ++ks) {
        const int k0 = ks * 32;
        // ---- stage B (w1 hi/lo tile, chunk-swizzled source) ----
#pragma unroll
        for (int i = 0; i < 4; ++i) {
            int slot = tid + 256 * i;
            int row = slot >> 2;
            int kc = (slot & 3) ^ ((row >> 1) & 3);
            size_t goff = (size_t)row * IN_C + k0 + kc * 8;
            int sbase = (w * 64 + 256 * i) * 8;
            gload16(w1h + goff, &sm.p1.Bh[sbase]);
            gload16(w1l + goff, &sm.p1.Bl[sbase]);
        }
        // ---- stage A from registers (no global latency) ----
#pragma unroll
        for (int i = 0; i < 2; ++i) {
            int f4 = tid + 256 * i;
            int r = f4 >> 3, kk = (f4 & 7) * 4;
            *(bf16x4*)&sm.p1.Ah[r * 40 + kk] = xh[ks][i];
        }
        __syncthreads();

        bf16x8 ah[4], bh[4], bl[4];
#pragma unroll
        for (int m = 0; m < 4; ++m)
            ah[m] = *(const bf16x8*)&sm.p1.Ah[(m * 16 + lr) * 40 + kg * 8];
#pragma unroll
        for (int nf = 0; nf < 4; ++nf) {
            int row = w * 64 + nf * 16 + lr;
            int kc = kg ^ ((row >> 1) & 3);
            int bo = row * 32 + kc * 8;
            bh[nf] = *(const bf16x8*)&sm.p1.Bh[bo];
            bl[nf] = *(const bf16x8*)&sm.p1.Bl[bo];
        }
#pragma unroll
        for (int m = 0; m < 4; ++m)
#pragma unroll
            for (int nf = 0; nf < 4; ++nf) {
                acc[m][nf] = MFMA(ah[m], bh[nf], acc[m][nf]);
                acc[m][nf] = MFMA(ah[m], bl[nf], acc[m][nf]);
            }
        __syncthreads();
    }

    // ---- epilogue 1: bias + relu, split to hi/lo H1 in LDS ----
#pragma unroll
    for (int m = 0; m < 4; ++m)
#pragma unroll
        for (int nf = 0; nf < 4; ++nf) {
            int col = w * 64 + nf * 16 + lr;
            float bb = b1[col];
#pragma unroll
            for (int r = 0; r < 4; ++r) {
                int row = m * 16 + kg * 4 + r;
                float hv = acc[m][nf][r] + bb;
                hv = fmaxf(hv, 0.0f);
                __bf16 hb = (__bf16)hv;
                sm.p2.Hh[row * 264 + col] = hb;
                sm.p2.Hl[row * 264 + col] = (__bf16)(hv - (float)hb);
            }
        }
    __syncthreads();

    // ---- phase 2: out[64][64] = H1 @ W2^T + b2 ----
    f32x4 acc2[4];
#pragma unroll
    for (int m = 0; m < 4; ++m) acc2[m] = (f32x4)0.0f;
    const int col2 = w * 16 + lr;

#pragma unroll
    for (int k0 = 0; k0 < HID_C; k0 += 32) {
        size_t wo = (size_t)col2 * HID_C + k0 + kg * 8;
        bf16x8 b2h = *(const bf16x8*)&w2h[wo];
        bf16x8 b2l = *(const bf16x8*)&w2l[wo];
#pragma unroll
        for (int m = 0; m < 4; ++m) {
            int ho = (m * 16 + lr) * 264 + k0 + kg * 8;
            bf16x8 a2h = *(const bf16x8*)&sm.p2.Hh[ho];
            bf16x8 a2l = *(const bf16x8*)&sm.p2.Hl[ho];
            acc2[m] = MFMA(a2h, b2h, acc2[m]);
            acc2[m] = MFMA(a2h, b2l, acc2[m]);
            acc2[m] = MFMA(a2l, b2h, acc2[m]);
        }
    }

    float bb2 = b2[col2];
#pragma unroll
    for (int m = 0; m < 4; ++m)
#pragma unroll
        for (int r = 0; r < 4; ++r) {
            int grow = row0 + m * 16 + kg * 4 + r;
            if (grow < n) {
                float vv = acc2[m][r] + bb2;
                size_t idx = (size_t)grow * OUT_C + col2;
                h016[idx] = (f16)vv;
                hcur16[idx] = (f16)vv;
            }
        }
}

// ---------------------------------------------------------------------------
// fp16 propagation v4: 4 nodes per wave, 16 lanes (= 64 channels as f16x4)
// per node. One gather instruction now fetches FOUR different 128B rows
// (one per 16-lane group). Edge metadata: each lane loads one int2 per
// 16-edge batch of its group; (src,w) broadcast within the group via shfl.
// Validity branch is uniform per group -> clean exec masking, no wasted
// gathers for finished groups.
// ---------------------------------------------------------------------------
__global__ __launch_bounds__(256) void k_prop16(const f16* __restrict__ hin,
                                                const f16* __restrict__ h016,
                                                f16* __restrict__ hout,
                                                float* __restrict__ dout,
                                                const int* __restrict__ row_ptr,
                                                const int2* __restrict__ csr_pack,
                                                const float* __restrict__ dinv,
                                                int n, int final_iter) {
    const int gwave = (blockIdx.x * blockDim.x + threadIdx.x) >> 6;
    const int lane = threadIdx.x & 63;
    const int g = lane >> 4;    // group 0..3 (node within wave)
    const int cl = lane & 15;   // channel slot: channels 4cl..4cl+3

    int node_raw = gwave * 4 + g;
    bool node_valid = node_raw < n;
    int node = node_valid ? node_raw : (n - 1);

    int e0 = row_ptr[node], e1 = row_ptr[node + 1];
    int cnt = e1 - e0;
    int nb = (cnt + 15) >> 4;
    // wave-max over the 4 groups (group id = lane bits 4,5)
    nb = max(nb, __shfl_xor(nb, 16));
    nb = max(nb, __shfl_xor(nb, 32));

    float a0 = 0.0f, a1 = 0.0f, a2 = 0.0f, a3 = 0.0f;
    const int gbase = g * 16;

    for (int b = 0; b < nb; ++b) {
        int mbase = e0 + b * 16;
        int midx = min(mbase + cl, N_EDGES - 1);
        int2 meta = csr_pack[midx];
#pragma unroll
        for (int j = 0; j < 16; ++j) {
            int s = __shfl(meta.x, gbase + j);
            float wv = __int_as_float(__shfl(meta.y, gbase + j));
            if (mbase + j < e1) {  // uniform within group
                f16x4 v = *(const f16x4*)&hin[(size_t)s * OUT_C + cl * 4];
                a0 += wv * (float)v.x;
                a1 += wv * (float)v.y;
                a2 += wv * (float)v.z;
                a3 += wv * (float)v.w;
            }
        }
    }

    float dv = dinv[node];
    float d2 = dv * dv;
    size_t idx = (size_t)node * OUT_C + cl * 4;
    f16x4 sv = *(const f16x4*)&hin[idx];
    f16x4 h0v = *(const f16x4*)&h016[idx];
    float r0 = (1.0f - ALPHA) * (a0 + d2 * (float)sv.x) + ALPHA * (float)h0v.x;
    float r1 = (1.0f - ALPHA) * (a1 + d2 * (float)sv.y) + ALPHA * (float)h0v.y;
    float r2 = (1.0f - ALPHA) * (a2 + d2 * (float)sv.z) + ALPHA * (float)h0v.z;
    float r3 = (1.0f - ALPHA) * (a3 + d2 * (float)sv.w) + ALPHA * (float)h0v.w;

    if (node_valid) {
        f16x4 o;
        o.x = (f16)r0;
        o.y = (f16)r1;
        o.z = (f16)r2;
        o.w = (f16)r3;
        *(f16x4*)&hout[idx] = o;
        if (final_iter) {
            float4 of = make_float4(r0, r1, r2, r3);
            *(float4*)&dout[idx] = of;
        }
    }
}

// ---------------------------------------------------------------------------
extern "C" void kernel_launch(void* const* d_in, const int* in_sizes, int n_in,
                              void* d_out, int out_size, void* d_ws, size_t ws_size,
                              hipStream_t stream) {
    const float* x  = (const float*)d_in[0];
    const int*   ei = (const int*)d_in[1];
    const float* w1 = (const float*)d_in[2];
    const float* b1 = (const float*)d_in[3];
    const float* w2 = (const float*)d_in[4];
    const float* b2 = (const float*)d_in[5];
    float* dout = (float*)d_out;

    const int N = N_NODES;
    const int E = N_EDGES;
    const int G = (N + SCB - 1) / SCB;  // 98 scan blocks

    // workspace layout
    f16*   h16A    = (f16*)d_ws;                   // N*64
    f16*   h16B    = h16A + (size_t)N * OUT_C;     // N*64
    f16*   h016    = h16B + (size_t)N * OUT_C;     // N*64
    int2*  csr_pack = (int2*)(h016 + (size_t)N * OUT_C);   // E int2
    float* dinv    = (float*)(csr_pack + E);       // N
    int*   cnt     = (int*)(dinv + N);             // N
    int*   row_ptr = cnt + N;                      // N+1
    int*   cursor  = row_ptr + (N + 1);            // N
    __bf16* w1h    = (__bf16*)(cursor + N);        // 256*512
    __bf16* w1l    = w1h + (size_t)HID_C * IN_C;   // 256*512
    __bf16* w2h    = w1l + (size_t)HID_C * IN_C;   // 64*256
    __bf16* w2l    = w2h + (size_t)OUT_C * HID_C;  // 64*256
    int*   bsum    = (int*)(w2l + (size_t)OUT_C * HID_C);  // 128
    int*   boff    = bsum + 128;                           // 128

    hipMemsetAsync(cnt, 0, (size_t)N * sizeof(int), stream);

    k_count<<<(E + 255) / 256, 256, 0, stream>>>(ei, cnt, E);
    k_dinv<<<(N + 255) / 256, 256, 0, stream>>>(cnt, dinv, N);
    k_scan1<<<G, 256, 0, stream>>>(cnt, bsum, N);
    k_scan2<<<1, 128, 0, stream>>>(bsum, boff, G, row_ptr, N, E);
    k_scan3<<<G, 256, 0, stream>>>(cnt, boff, row_ptr, cursor, N);
    k_fill<<<(E + 255) / 256, 256, 0, stream>>>(ei, dinv, cursor, csr_pack, E);

    k_split<<<(HID_C * IN_C + 255) / 256, 256, 0, stream>>>(w1, w1h, w1l, HID_C * IN_C);
    k_split<<<(OUT_C * HID_C + 255) / 256, 256, 0, stream>>>(w2, w2h, w2l, OUT_C * HID_C);

    k_mlp2<<<(N + 63) / 64, 256, 0, stream>>>(x, w1h, w1l, b1, w2h, w2l, b2, h016, h16A, N);

    const int pwaves = (N + 3) / 4;                 // 25000 waves
    const int pblocks = (pwaves * 64 + 255) / 256;  // 6250 blocks
    for (int it = 0; it < K_ITERS; ++it) {
        const f16* pin = (it & 1) ? h16B : h16A;
        f16* pout = (it & 1) ? h16A : h16B;
        k_prop16<<<pblocks, 256, 0, stream>>>(pin, h016, pout, dout, row_ptr,
                                              csr_pack, dinv, N,
                                              it == K_ITERS - 1 ? 1 : 0);
    }
}

// Round 8
// 746.879 us; speedup vs baseline: 1.5373x; 1.0704x over previous
//
#include <hip/hip_runtime.h>
#include <hip/hip_bf16.h>

#define N_NODES 100000
#define N_EDGES 1600000
#define IN_C 512
#define HID_C 256
#define OUT_C 64
#define K_ITERS 10
#define ALPHA 0.1f

typedef float f32x4 __attribute__((ext_vector_type(4)));
typedef _Float16 f16;
typedef _Float16 f16x4 __attribute__((ext_vector_type(4)));
typedef _Float16 f16x8 __attribute__((ext_vector_type(8)));

#define MFMA16(a, b, c) __builtin_amdgcn_mfma_f32_16x16x32_f16((a), (b), (c), 0, 0, 0)

__device__ __forceinline__ void gload16(const void* g, void* l) {
    __builtin_amdgcn_global_load_lds(
        (const __attribute__((address_space(1))) unsigned int*)g,
        (__attribute__((address_space(3))) unsigned int*)l, 16, 0, 0);
}

// ---------------------------------------------------------------------------
// CSR build kernels
// ---------------------------------------------------------------------------
__global__ void k_count(const int* __restrict__ ei, int* __restrict__ cnt, int E) {
    int e = blockIdx.x * blockDim.x + threadIdx.x;
    if (e < E) atomicAdd(&cnt[ei[E + e]], 1);
}

__global__ void k_dinv(const int* __restrict__ cnt, float* __restrict__ dinv, int n) {
    int i = blockIdx.x * blockDim.x + threadIdx.x;
    if (i < n) dinv[i] = rsqrtf((float)cnt[i] + 1.0f);  // +1 for self-loop
}

// ---------------------------------------------------------------------------
// Two-level scan: 1024 elems/block (256 thr x 4).
// ---------------------------------------------------------------------------
#define SCB 1024
__global__ __launch_bounds__(256) void k_scan1(const int* __restrict__ cnt,
                                               int* __restrict__ bsum, int n) {
    __shared__ int s[256];
    int b = blockIdx.x, t = threadIdx.x;
    int base = b * SCB + t * 4;
    int local = 0;
#pragma unroll
    for (int j = 0; j < 4; ++j) {
        int i = base + j;
        if (i < n) local += cnt[i];
    }
    s[t] = local;
    __syncthreads();
    for (int off = 1; off < 256; off <<= 1) {
        int u = (t >= off) ? s[t - off] : 0;
        __syncthreads();
        s[t] += u;
        __syncthreads();
    }
    if (t == 255) bsum[b] = s[255];
}

__global__ __launch_bounds__(128) void k_scan2(const int* __restrict__ bsum,
                                               int* __restrict__ boff, int G,
                                               int* __restrict__ row_ptr, int n, int total) {
    __shared__ int s[128];
    int t = threadIdx.x;
    int v = (t < G) ? bsum[t] : 0;
    s[t] = v;
    __syncthreads();
    for (int off = 1; off < 128; off <<= 1) {
        int u = (t >= off) ? s[t - off] : 0;
        __syncthreads();
        s[t] += u;
        __syncthreads();
    }
    if (t < G) boff[t] = s[t] - v;
    if (t == 0) row_ptr[n] = total;
}

__global__ __launch_bounds__(256) void k_scan3(const int* __restrict__ cnt,
                                               const int* __restrict__ boff,
                                               int* __restrict__ row_ptr,
                                               int* __restrict__ cursor, int n) {
    __shared__ int s[256];
    int b = blockIdx.x, t = threadIdx.x;
    int base = b * SCB + t * 4;
    int c4[4];
    int local = 0;
#pragma unroll
    for (int j = 0; j < 4; ++j) {
        int i = base + j;
        c4[j] = (i < n) ? cnt[i] : 0;
        local += c4[j];
    }
    s[t] = local;
    __syncthreads();
    for (int off = 1; off < 256; off <<= 1) {
        int u = (t >= off) ? s[t - off] : 0;
        __syncthreads();
        s[t] += u;
        __syncthreads();
    }
    int run = boff[b] + s[t] - local;
#pragma unroll
    for (int j = 0; j < 4; ++j) {
        int i = base + j;
        if (i < n) {
            row_ptr[i] = run;
            cursor[i] = run;
            run += c4[j];
        }
    }
}

// k_fill writes packed (src, weight) metadata: one 8B load per edge later.
__global__ void k_fill(const int* __restrict__ ei, const float* __restrict__ dinv,
                       int* __restrict__ cursor, int2* __restrict__ csr_pack, int E) {
    int e = blockIdx.x * blockDim.x + threadIdx.x;
    if (e < E) {
        int s = ei[e];
        int d = ei[E + e];
        int pos = atomicAdd(&cursor[d], 1);
        csr_pack[pos] = make_int2(s, __float_as_int(dinv[s] * dinv[d]));
    }
}

// ---------------------------------------------------------------------------
// Weight split: f32 -> (hi f16, lo f16), hi+lo ~ f32 to ~2^-21 rel.
// ---------------------------------------------------------------------------
__global__ void k_split(const float* __restrict__ in, f16* __restrict__ hi,
                        f16* __restrict__ lo, int n) {
    int i = blockIdx.x * blockDim.x + threadIdx.x;
    if (i < n) {
        float f = in[i];
        f16 h = (f16)f;
        hi[i] = h;
        lo[i] = (f16)(f - (float)h);
    }
}

// ---------------------------------------------------------------------------
// Fused split-f16 MFMA MLP v3.
// Back to v1 structure (in-loop x loads), but:
//  - f16 MFMA (16x16x32_f16), 2-term splits: A-hi * (W-hi + W-lo).
//    f16's 10 mantissa bits give rel err ~2.4e-4 (better than bf16 3-term
//    for A, and W split to ~2^-21). Layer-1 MFMA 48 -> 32 per k-step.
//  - H1 stored f16 single-copy (no lo) -> phase-2 LDS halves to 33.8 KB.
//  - LDS = max(5+16+16, 33.8) = 37.9 KB -> 4 blocks/CU (was 2). Doubles the
//    waves available to hide the per-step gload16 vmcnt(0)+barrier drain.
// ---------------------------------------------------------------------------
__global__ __launch_bounds__(256, 4) void k_mlp2(
    const float* __restrict__ x,
    const f16* __restrict__ w1h, const f16* __restrict__ w1l,
    const float* __restrict__ b1,
    const f16* __restrict__ w2h, const f16* __restrict__ w2l,
    const float* __restrict__ b2,
    f16* __restrict__ h016, f16* __restrict__ hcur16, int n) {
    __shared__ __align__(16) union {
        struct {
            f16 Ah[64 * 40];   // 5 KB, rows padded to 40
            f16 Bh[256 * 32];  // 16 KB, chunk-swizzled
            f16 Bl[256 * 32];  // 16 KB
        } p1;
        struct {
            f16 Hh[64 * 264];  // 33.8 KB, rows padded to 264
        } p2;
    } sm;

    const int tid = threadIdx.x;
    const int l = tid & 63;
    const int w = tid >> 6;
    const int lr = l & 15;
    const int kg = l >> 4;
    const int row0 = blockIdx.x * 64;

    f32x4 acc[4][4];
#pragma unroll
    for (int m = 0; m < 4; ++m)
#pragma unroll
        for (int nf = 0; nf < 4; ++nf) acc[m][nf] = (f32x4)0.0f;

    for (int k0 = 0; k0 < IN_C; k0 += 32) {
        // ---- stage B (w1 hi/lo tile, chunk-swizzled source) ----
#pragma unroll
        for (int i = 0; i < 4; ++i) {
            int slot = tid + 256 * i;
            int row = slot >> 2;
            int kc = (slot & 3) ^ ((row >> 1) & 3);
            size_t goff = (size_t)row * IN_C + k0 + kc * 8;
            int sbase = (w * 64 + 256 * i) * 8;
            gload16(w1h + goff, &sm.p1.Bh[sbase]);
            gload16(w1l + goff, &sm.p1.Bl[sbase]);
        }
        // ---- stage A (x rows, f32 -> f16-hi) ----
#pragma unroll
        for (int i = 0; i < 2; ++i) {
            int f4 = tid + 256 * i;
            int r = f4 >> 3, kk = (f4 & 7) * 4;
            int gr = row0 + r;
            if (gr >= n) gr = n - 1;
            float4 v = *(const float4*)&x[(size_t)gr * IN_C + k0 + kk];
            f16x4 h4;
            h4.x = (f16)v.x;
            h4.y = (f16)v.y;
            h4.z = (f16)v.z;
            h4.w = (f16)v.w;
            *(f16x4*)&sm.p1.Ah[r * 40 + kk] = h4;
        }
        __syncthreads();

        f16x8 ah[4], bh[4], bl[4];
#pragma unroll
        for (int m = 0; m < 4; ++m)
            ah[m] = *(const f16x8*)&sm.p1.Ah[(m * 16 + lr) * 40 + kg * 8];
#pragma unroll
        for (int nf = 0; nf < 4; ++nf) {
            int row = w * 64 + nf * 16 + lr;
            int kc = kg ^ ((row >> 1) & 3);
            int bo = row * 32 + kc * 8;
            bh[nf] = *(const f16x8*)&sm.p1.Bh[bo];
            bl[nf] = *(const f16x8*)&sm.p1.Bl[bo];
        }
#pragma unroll
        for (int m = 0; m < 4; ++m)
#pragma unroll
            for (int nf = 0; nf < 4; ++nf) {
                acc[m][nf] = MFMA16(ah[m], bh[nf], acc[m][nf]);
                acc[m][nf] = MFMA16(ah[m], bl[nf], acc[m][nf]);
            }
        __syncthreads();
    }

    // ---- epilogue 1: bias + relu -> f16 H1 in LDS ----
#pragma unroll
    for (int m = 0; m < 4; ++m)
#pragma unroll
        for (int nf = 0; nf < 4; ++nf) {
            int col = w * 64 + nf * 16 + lr;
            float bb = b1[col];
#pragma unroll
            for (int r = 0; r < 4; ++r) {
                int row = m * 16 + kg * 4 + r;
                float hv = acc[m][nf][r] + bb;
                hv = fmaxf(hv, 0.0f);
                sm.p2.Hh[row * 264 + col] = (f16)hv;
            }
        }
    __syncthreads();

    // ---- phase 2: out[64][64] = H1 @ W2^T + b2 ----
    f32x4 acc2[4];
#pragma unroll
    for (int m = 0; m < 4; ++m) acc2[m] = (f32x4)0.0f;
    const int col2 = w * 16 + lr;

#pragma unroll
    for (int k0 = 0; k0 < HID_C; k0 += 32) {
        size_t wo = (size_t)col2 * HID_C + k0 + kg * 8;
        f16x8 b2h = *(const f16x8*)&w2h[wo];
        f16x8 b2l = *(const f16x8*)&w2l[wo];
#pragma unroll
        for (int m = 0; m < 4; ++m) {
            f16x8 a2h = *(const f16x8*)&sm.p2.Hh[(m * 16 + lr) * 264 + k0 + kg * 8];
            acc2[m] = MFMA16(a2h, b2h, acc2[m]);
            acc2[m] = MFMA16(a2h, b2l, acc2[m]);
        }
    }

    float bb2 = b2[col2];
#pragma unroll
    for (int m = 0; m < 4; ++m)
#pragma unroll
        for (int r = 0; r < 4; ++r) {
            int grow = row0 + m * 16 + kg * 4 + r;
            if (grow < n) {
                float vv = acc2[m][r] + bb2;
                size_t idx = (size_t)grow * OUT_C + col2;
                h016[idx] = (f16)vv;
                hcur16[idx] = (f16)vv;
            }
        }
}

// ---------------------------------------------------------------------------
// fp16 propagation v4 (unchanged from round 7): 4 nodes per wave, 16 lanes
// (= 64 channels as f16x4) per node; one gather instruction fetches FOUR
// different 128B rows. Metadata broadcast within 16-lane groups via shfl.
// ---------------------------------------------------------------------------
__global__ __launch_bounds__(256) void k_prop16(const f16* __restrict__ hin,
                                                const f16* __restrict__ h016,
                                                f16* __restrict__ hout,
                                                float* __restrict__ dout,
                                                const int* __restrict__ row_ptr,
                                                const int2* __restrict__ csr_pack,
                                                const float* __restrict__ dinv,
                                                int n, int final_iter) {
    const int gwave = (blockIdx.x * blockDim.x + threadIdx.x) >> 6;
    const int lane = threadIdx.x & 63;
    const int g = lane >> 4;    // group 0..3 (node within wave)
    const int cl = lane & 15;   // channel slot: channels 4cl..4cl+3

    int node_raw = gwave * 4 + g;
    bool node_valid = node_raw < n;
    int node = node_valid ? node_raw : (n - 1);

    int e0 = row_ptr[node], e1 = row_ptr[node + 1];
    int cnt = e1 - e0;
    int nb = (cnt + 15) >> 4;
    nb = max(nb, __shfl_xor(nb, 16));
    nb = max(nb, __shfl_xor(nb, 32));

    float a0 = 0.0f, a1 = 0.0f, a2 = 0.0f, a3 = 0.0f;
    const int gbase = g * 16;

    for (int b = 0; b < nb; ++b) {
        int mbase = e0 + b * 16;
        int midx = min(mbase + cl, N_EDGES - 1);
        int2 meta = csr_pack[midx];
#pragma unroll
        for (int j = 0; j < 16; ++j) {
            int s = __shfl(meta.x, gbase + j);
            float wv = __int_as_float(__shfl(meta.y, gbase + j));
            if (mbase + j < e1) {  // uniform within group
                f16x4 v = *(const f16x4*)&hin[(size_t)s * OUT_C + cl * 4];
                a0 += wv * (float)v.x;
                a1 += wv * (float)v.y;
                a2 += wv * (float)v.z;
                a3 += wv * (float)v.w;
            }
        }
    }

    float dv = dinv[node];
    float d2 = dv * dv;
    size_t idx = (size_t)node * OUT_C + cl * 4;
    f16x4 sv = *(const f16x4*)&hin[idx];
    f16x4 h0v = *(const f16x4*)&h016[idx];
    float r0 = (1.0f - ALPHA) * (a0 + d2 * (float)sv.x) + ALPHA * (float)h0v.x;
    float r1 = (1.0f - ALPHA) * (a1 + d2 * (float)sv.y) + ALPHA * (float)h0v.y;
    float r2 = (1.0f - ALPHA) * (a2 + d2 * (float)sv.z) + ALPHA * (float)h0v.z;
    float r3 = (1.0f - ALPHA) * (a3 + d2 * (float)sv.w) + ALPHA * (float)h0v.w;

    if (node_valid) {
        f16x4 o;
        o.x = (f16)r0;
        o.y = (f16)r1;
        o.z = (f16)r2;
        o.w = (f16)r3;
        *(f16x4*)&hout[idx] = o;
        if (final_iter) {
            float4 of = make_float4(r0, r1, r2, r3);
            *(float4*)&dout[idx] = of;
        }
    }
}

// ---------------------------------------------------------------------------
extern "C" void kernel_launch(void* const* d_in, const int* in_sizes, int n_in,
                              void* d_out, int out_size, void* d_ws, size_t ws_size,
                              hipStream_t stream) {
    const float* x  = (const float*)d_in[0];
    const int*   ei = (const int*)d_in[1];
    const float* w1 = (const float*)d_in[2];
    const float* b1 = (const float*)d_in[3];
    const float* w2 = (const float*)d_in[4];
    const float* b2 = (const float*)d_in[5];
    float* dout = (float*)d_out;

    const int N = N_NODES;
    const int E = N_EDGES;
    const int G = (N + SCB - 1) / SCB;  // 98 scan blocks

    // workspace layout
    f16*   h16A    = (f16*)d_ws;                   // N*64
    f16*   h16B    = h16A + (size_t)N * OUT_C;     // N*64
    f16*   h016    = h16B + (size_t)N * OUT_C;     // N*64
    int2*  csr_pack = (int2*)(h016 + (size_t)N * OUT_C);   // E int2
    float* dinv    = (float*)(csr_pack + E);       // N
    int*   cnt     = (int*)(dinv + N);             // N
    int*   row_ptr = cnt + N;                      // N+1
    int*   cursor  = row_ptr + (N + 1);            // N
    f16*   w1h     = (f16*)(cursor + N);           // 256*512
    f16*   w1l     = w1h + (size_t)HID_C * IN_C;   // 256*512
    f16*   w2h     = w1l + (size_t)HID_C * IN_C;   // 64*256
    f16*   w2l     = w2h + (size_t)OUT_C * HID_C;  // 64*256
    int*   bsum    = (int*)(w2l + (size_t)OUT_C * HID_C);  // 128
    int*   boff    = bsum + 128;                           // 128

    hipMemsetAsync(cnt, 0, (size_t)N * sizeof(int), stream);

    k_count<<<(E + 255) / 256, 256, 0, stream>>>(ei, cnt, E);
    k_dinv<<<(N + 255) / 256, 256, 0, stream>>>(cnt, dinv, N);
    k_scan1<<<G, 256, 0, stream>>>(cnt, bsum, N);
    k_scan2<<<1, 128, 0, stream>>>(bsum, boff, G, row_ptr, N, E);
    k_scan3<<<G, 256, 0, stream>>>(cnt, boff, row_ptr, cursor, N);
    k_fill<<<(E + 255) / 256, 256, 0, stream>>>(ei, dinv, cursor, csr_pack, E);

    k_split<<<(HID_C * IN_C + 255) / 256, 256, 0, stream>>>(w1, w1h, w1l, HID_C * IN_C);
    k_split<<<(OUT_C * HID_C + 255) / 256, 256, 0, stream>>>(w2, w2h, w2l, OUT_C * HID_C);

    k_mlp2<<<(N + 63) / 64, 256, 0, stream>>>(x, w1h, w1l, b1, w2h, w2l, b2, h016, h16A, N);

    const int pwaves = (N + 3) / 4;                 // 25000 waves
    const int pblocks = (pwaves * 64 + 255) / 256;  // 6250 blocks
    for (int it = 0; it < K_ITERS; ++it) {
        const f16* pin = (it & 1) ? h16B : h16A;
        f16* pout = (it & 1) ? h16A : h16B;
        k_prop16<<<pblocks, 256, 0, stream>>>(pin, h016, pout, dout, row_ptr,
                                              csr_pack, dinv, N,
                                              it == K_ITERS - 1 ? 1 : 0);
    }
}

// Round 9
// 637.750 us; speedup vs baseline: 1.8003x; 1.1711x over previous
//
#include <hip/hip_runtime.h>
#include <hip/hip_bf16.h>

#define N_NODES 100000
#define N_EDGES 1600000
#define IN_C 512
#define HID_C 256
#define OUT_C 64
#define K_ITERS 10
#define ALPHA 0.1f

typedef float f32x4 __attribute__((ext_vector_type(4)));
typedef _Float16 f16;
typedef _Float16 f16x4 __attribute__((ext_vector_type(4)));
typedef _Float16 f16x8 __attribute__((ext_vector_type(8)));

#define MFMA16(a, b, c) __builtin_amdgcn_mfma_f32_16x16x32_f16((a), (b), (c), 0, 0, 0)

__device__ __forceinline__ void gload16(const void* g, void* l) {
    __builtin_amdgcn_global_load_lds(
        (const __attribute__((address_space(1))) unsigned int*)g,
        (__attribute__((address_space(3))) unsigned int*)l, 16, 0, 0);
}

// ---------------------------------------------------------------------------
// CSR build kernels
// ---------------------------------------------------------------------------
__global__ void k_count(const int* __restrict__ ei, int* __restrict__ cnt, int E) {
    int e = blockIdx.x * blockDim.x + threadIdx.x;
    if (e < E) atomicAdd(&cnt[ei[E + e]], 1);
}

__global__ void k_dinv(const int* __restrict__ cnt, float* __restrict__ dinv, int n) {
    int i = blockIdx.x * blockDim.x + threadIdx.x;
    if (i < n) dinv[i] = rsqrtf((float)cnt[i] + 1.0f);  // +1 for self-loop
}

// ---------------------------------------------------------------------------
// Two-level scan: 1024 elems/block (256 thr x 4).
// ---------------------------------------------------------------------------
#define SCB 1024
__global__ __launch_bounds__(256) void k_scan1(const int* __restrict__ cnt,
                                               int* __restrict__ bsum, int n) {
    __shared__ int s[256];
    int b = blockIdx.x, t = threadIdx.x;
    int base = b * SCB + t * 4;
    int local = 0;
#pragma unroll
    for (int j = 0; j < 4; ++j) {
        int i = base + j;
        if (i < n) local += cnt[i];
    }
    s[t] = local;
    __syncthreads();
    for (int off = 1; off < 256; off <<= 1) {
        int u = (t >= off) ? s[t - off] : 0;
        __syncthreads();
        s[t] += u;
        __syncthreads();
    }
    if (t == 255) bsum[b] = s[255];
}

__global__ __launch_bounds__(128) void k_scan2(const int* __restrict__ bsum,
                                               int* __restrict__ boff, int G,
                                               int* __restrict__ row_ptr, int n, int total) {
    __shared__ int s[128];
    int t = threadIdx.x;
    int v = (t < G) ? bsum[t] : 0;
    s[t] = v;
    __syncthreads();
    for (int off = 1; off < 128; off <<= 1) {
        int u = (t >= off) ? s[t - off] : 0;
        __syncthreads();
        s[t] += u;
        __syncthreads();
    }
    if (t < G) boff[t] = s[t] - v;
    if (t == 0) row_ptr[n] = total;
}

__global__ __launch_bounds__(256) void k_scan3(const int* __restrict__ cnt,
                                               const int* __restrict__ boff,
                                               int* __restrict__ row_ptr,
                                               int* __restrict__ cursor, int n) {
    __shared__ int s[256];
    int b = blockIdx.x, t = threadIdx.x;
    int base = b * SCB + t * 4;
    int c4[4];
    int local = 0;
#pragma unroll
    for (int j = 0; j < 4; ++j) {
        int i = base + j;
        c4[j] = (i < n) ? cnt[i] : 0;
        local += c4[j];
    }
    s[t] = local;
    __syncthreads();
    for (int off = 1; off < 256; off <<= 1) {
        int u = (t >= off) ? s[t - off] : 0;
        __syncthreads();
        s[t] += u;
        __syncthreads();
    }
    int run = boff[b] + s[t] - local;
#pragma unroll
    for (int j = 0; j < 4; ++j) {
        int i = base + j;
        if (i < n) {
            row_ptr[i] = run;
            cursor[i] = run;
            run += c4[j];
        }
    }
}

// k_fill writes packed (src, weight) metadata: one 8B load per edge later.
__global__ void k_fill(const int* __restrict__ ei, const float* __restrict__ dinv,
                       int* __restrict__ cursor, int2* __restrict__ csr_pack, int E) {
    int e = blockIdx.x * blockDim.x + threadIdx.x;
    if (e < E) {
        int s = ei[e];
        int d = ei[E + e];
        int pos = atomicAdd(&cursor[d], 1);
        csr_pack[pos] = make_int2(s, __float_as_int(dinv[s] * dinv[d]));
    }
}

// ---------------------------------------------------------------------------
// Weight cast: f32 -> f16 (single precision term; rel err ~4.9e-4).
// ---------------------------------------------------------------------------
__global__ void k_cast(const float* __restrict__ in, f16* __restrict__ out, int n) {
    int i = blockIdx.x * blockDim.x + threadIdx.x;
    if (i < n) out[i] = (f16)in[i];
}

// ---------------------------------------------------------------------------
// Fused f16 MFMA MLP v4.
// vs v3: single-term f16 weights (no lo split). Staged bytes per k-step halve
// (Bh only, 16 KB), layer-1 MFMA 16/step, layer-2 32 total. LDS = max(5+16,
// 33.8) = 33.8 KB -> 4 blocks/CU. Numerics: weight rounding 2^-11 rel ->
// ~1e-3 abs on final output (threshold margin 2x+ retained).
// ---------------------------------------------------------------------------
__global__ __launch_bounds__(256, 4) void k_mlp2(
    const float* __restrict__ x,
    const f16* __restrict__ w1h,
    const float* __restrict__ b1,
    const f16* __restrict__ w2h,
    const float* __restrict__ b2,
    f16* __restrict__ h016, f16* __restrict__ hcur16, int n) {
    __shared__ __align__(16) union {
        struct {
            f16 Ah[64 * 40];   // 5 KB, rows padded to 40
            f16 Bh[256 * 32];  // 16 KB, chunk-swizzled
        } p1;
        struct {
            f16 Hh[64 * 264];  // 33.8 KB, rows padded to 264
        } p2;
    } sm;

    const int tid = threadIdx.x;
    const int l = tid & 63;
    const int w = tid >> 6;
    const int lr = l & 15;
    const int kg = l >> 4;
    const int row0 = blockIdx.x * 64;

    f32x4 acc[4][4];
#pragma unroll
    for (int m = 0; m < 4; ++m)
#pragma unroll
        for (int nf = 0; nf < 4; ++nf) acc[m][nf] = (f32x4)0.0f;

    for (int k0 = 0; k0 < IN_C; k0 += 32) {
        // ---- stage B (w1 f16 tile, chunk-swizzled source) ----
#pragma unroll
        for (int i = 0; i < 4; ++i) {
            int slot = tid + 256 * i;
            int row = slot >> 2;
            int kc = (slot & 3) ^ ((row >> 1) & 3);
            size_t goff = (size_t)row * IN_C + k0 + kc * 8;
            int sbase = (w * 64 + 256 * i) * 8;
            gload16(w1h + goff, &sm.p1.Bh[sbase]);
        }
        // ---- stage A (x rows, f32 -> f16) ----
#pragma unroll
        for (int i = 0; i < 2; ++i) {
            int f4 = tid + 256 * i;
            int r = f4 >> 3, kk = (f4 & 7) * 4;
            int gr = row0 + r;
            if (gr >= n) gr = n - 1;
            float4 v = *(const float4*)&x[(size_t)gr * IN_C + k0 + kk];
            f16x4 h4;
            h4.x = (f16)v.x;
            h4.y = (f16)v.y;
            h4.z = (f16)v.z;
            h4.w = (f16)v.w;
            *(f16x4*)&sm.p1.Ah[r * 40 + kk] = h4;
        }
        __syncthreads();

        f16x8 ah[4], bh[4];
#pragma unroll
        for (int m = 0; m < 4; ++m)
            ah[m] = *(const f16x8*)&sm.p1.Ah[(m * 16 + lr) * 40 + kg * 8];
#pragma unroll
        for (int nf = 0; nf < 4; ++nf) {
            int row = w * 64 + nf * 16 + lr;
            int kc = kg ^ ((row >> 1) & 3);
            bh[nf] = *(const f16x8*)&sm.p1.Bh[row * 32 + kc * 8];
        }
#pragma unroll
        for (int m = 0; m < 4; ++m)
#pragma unroll
            for (int nf = 0; nf < 4; ++nf)
                acc[m][nf] = MFMA16(ah[m], bh[nf], acc[m][nf]);
        __syncthreads();
    }

    // ---- epilogue 1: bias + relu -> f16 H1 in LDS ----
#pragma unroll
    for (int m = 0; m < 4; ++m)
#pragma unroll
        for (int nf = 0; nf < 4; ++nf) {
            int col = w * 64 + nf * 16 + lr;
            float bb = b1[col];
#pragma unroll
            for (int r = 0; r < 4; ++r) {
                int row = m * 16 + kg * 4 + r;
                float hv = acc[m][nf][r] + bb;
                hv = fmaxf(hv, 0.0f);
                sm.p2.Hh[row * 264 + col] = (f16)hv;
            }
        }
    __syncthreads();

    // ---- phase 2: out[64][64] = H1 @ W2^T + b2 ----
    f32x4 acc2[4];
#pragma unroll
    for (int m = 0; m < 4; ++m) acc2[m] = (f32x4)0.0f;
    const int col2 = w * 16 + lr;

#pragma unroll
    for (int k0 = 0; k0 < HID_C; k0 += 32) {
        f16x8 b2h = *(const f16x8*)&w2h[(size_t)col2 * HID_C + k0 + kg * 8];
#pragma unroll
        for (int m = 0; m < 4; ++m) {
            f16x8 a2h = *(const f16x8*)&sm.p2.Hh[(m * 16 + lr) * 264 + k0 + kg * 8];
            acc2[m] = MFMA16(a2h, b2h, acc2[m]);
        }
    }

    float bb2 = b2[col2];
#pragma unroll
    for (int m = 0; m < 4; ++m)
#pragma unroll
        for (int r = 0; r < 4; ++r) {
            int grow = row0 + m * 16 + kg * 4 + r;
            if (grow < n) {
                float vv = acc2[m][r] + bb2;
                size_t idx = (size_t)grow * OUT_C + col2;
                h016[idx] = (f16)vv;
                hcur16[idx] = (f16)vv;
            }
        }
}

// ---------------------------------------------------------------------------
// fp16 propagation v5: 8 nodes per wave, 8 lanes (= 64 channels as f16x8)
// per node. One gather instruction fetches EIGHT different 128B rows.
// Metadata: per 8-edge batch each lane loads one int2; (src,w) broadcast
// within 8-lane groups via shfl. Validity uniform per group -> exec masking.
// ---------------------------------------------------------------------------
__global__ __launch_bounds__(256) void k_prop16(const f16* __restrict__ hin,
                                                const f16* __restrict__ h016,
                                                f16* __restrict__ hout,
                                                float* __restrict__ dout,
                                                const int* __restrict__ row_ptr,
                                                const int2* __restrict__ csr_pack,
                                                const float* __restrict__ dinv,
                                                int n, int final_iter) {
    const int gwave = (blockIdx.x * blockDim.x + threadIdx.x) >> 6;
    const int lane = threadIdx.x & 63;
    const int g = lane >> 3;   // group 0..7 (node within wave)
    const int cl = lane & 7;   // channel octet: channels 8cl..8cl+7

    int node_raw = gwave * 8 + g;
    bool node_valid = node_raw < n;
    int node = node_valid ? node_raw : (n - 1);

    int e0 = row_ptr[node], e1 = row_ptr[node + 1];
    int nb = (e1 - e0 + 7) >> 3;
    // wave-max over the 8 groups (group id = lane bits 3..5)
    nb = max(nb, __shfl_xor(nb, 8));
    nb = max(nb, __shfl_xor(nb, 16));
    nb = max(nb, __shfl_xor(nb, 32));

    float a[8];
#pragma unroll
    for (int q = 0; q < 8; ++q) a[q] = 0.0f;
    const int gbase = g * 8;

    for (int b = 0; b < nb; ++b) {
        int mbase = e0 + b * 8;
        int midx = min(mbase + cl, N_EDGES - 1);
        int2 meta = csr_pack[midx];
#pragma unroll
        for (int j = 0; j < 8; ++j) {
            int s = __shfl(meta.x, gbase + j);
            float wv = __int_as_float(__shfl(meta.y, gbase + j));
            if (mbase + j < e1) {  // uniform within group
                f16x8 v = *(const f16x8*)&hin[(size_t)s * OUT_C + cl * 8];
#pragma unroll
                for (int q = 0; q < 8; ++q) a[q] += wv * (float)v[q];
            }
        }
    }

    float dv = dinv[node];
    float d2 = dv * dv;
    size_t idx = (size_t)node * OUT_C + cl * 8;
    f16x8 sv = *(const f16x8*)&hin[idx];
    f16x8 h0v = *(const f16x8*)&h016[idx];
    float r[8];
#pragma unroll
    for (int q = 0; q < 8; ++q)
        r[q] = (1.0f - ALPHA) * (a[q] + d2 * (float)sv[q]) + ALPHA * (float)h0v[q];

    if (node_valid) {
        f16x8 o;
#pragma unroll
        for (int q = 0; q < 8; ++q) o[q] = (f16)r[q];
        *(f16x8*)&hout[idx] = o;
        if (final_iter) {
            float4 o0 = make_float4(r[0], r[1], r[2], r[3]);
            float4 o1 = make_float4(r[4], r[5], r[6], r[7]);
            *(float4*)&dout[idx] = o0;
            *(float4*)&dout[idx + 4] = o1;
        }
    }
}

// ---------------------------------------------------------------------------
extern "C" void kernel_launch(void* const* d_in, const int* in_sizes, int n_in,
                              void* d_out, int out_size, void* d_ws, size_t ws_size,
                              hipStream_t stream) {
    const float* x  = (const float*)d_in[0];
    const int*   ei = (const int*)d_in[1];
    const float* w1 = (const float*)d_in[2];
    const float* b1 = (const float*)d_in[3];
    const float* w2 = (const float*)d_in[4];
    const float* b2 = (const float*)d_in[5];
    float* dout = (float*)d_out;

    const int N = N_NODES;
    const int E = N_EDGES;
    const int G = (N + SCB - 1) / SCB;  // 98 scan blocks

    // workspace layout
    f16*   h16A    = (f16*)d_ws;                   // N*64
    f16*   h16B    = h16A + (size_t)N * OUT_C;     // N*64
    f16*   h016    = h16B + (size_t)N * OUT_C;     // N*64
    int2*  csr_pack = (int2*)(h016 + (size_t)N * OUT_C);   // E int2
    float* dinv    = (float*)(csr_pack + E);       // N
    int*   cnt     = (int*)(dinv + N);             // N
    int*   row_ptr = cnt + N;                      // N+1
    int*   cursor  = row_ptr + (N + 1);            // N
    f16*   w1h     = (f16*)(cursor + N);           // 256*512
    f16*   w2h     = w1h + (size_t)HID_C * IN_C;   // 64*256
    int*   bsum    = (int*)(w2h + (size_t)OUT_C * HID_C);  // 128
    int*   boff    = bsum + 128;                           // 128

    hipMemsetAsync(cnt, 0, (size_t)N * sizeof(int), stream);

    k_count<<<(E + 255) / 256, 256, 0, stream>>>(ei, cnt, E);
    k_dinv<<<(N + 255) / 256, 256, 0, stream>>>(cnt, dinv, N);
    k_scan1<<<G, 256, 0, stream>>>(cnt, bsum, N);
    k_scan2<<<1, 128, 0, stream>>>(bsum, boff, G, row_ptr, N, E);
    k_scan3<<<G, 256, 0, stream>>>(cnt, boff, row_ptr, cursor, N);
    k_fill<<<(E + 255) / 256, 256, 0, stream>>>(ei, dinv, cursor, csr_pack, E);

    k_cast<<<(HID_C * IN_C + 255) / 256, 256, 0, stream>>>(w1, w1h, HID_C * IN_C);
    k_cast<<<(OUT_C * HID_C + 255) / 256, 256, 0, stream>>>(w2, w2h, OUT_C * HID_C);

    k_mlp2<<<(N + 63) / 64, 256, 0, stream>>>(x, w1h, b1, w2h, b2, h016, h16A, N);

    const int pwaves = (N + 7) / 8;                 // 12500 waves
    const int pblocks = (pwaves * 64 + 255) / 256;  // 3125 blocks
    for (int it = 0; it < K_ITERS; ++it) {
        const f16* pin = (it & 1) ? h16B : h16A;
        f16* pout = (it & 1) ? h16A : h16B;
        k_prop16<<<pblocks, 256, 0, stream>>>(pin, h016, pout, dout, row_ptr,
                                              csr_pack, dinv, N,
                                              it == K_ITERS - 1 ? 1 : 0);
    }
}